// Round 8
// baseline (215.413 us; speedup 1.0000x reference)
//
#include <hip/hip_runtime.h>
#include <cstdint>
#include <cstddef>

#define B_ 16
#define Q_ 4096
#define G_ 128
#define C_ 80
#define QCHUNK 16
#define NCH (Q_ / QCHUNK)   // 256 chunks

typedef unsigned long long u64;
#define U64MAX 0xffffffffffffffffull

// pack (cost,q) into a sortable u64 key: asc key order == lex (cost asc, q asc)
__device__ __forceinline__ u64 packkey(float v, int q) {
    unsigned int bts = __float_as_uint(v);
    if (bts == 0x80000000u) bts = 0u;  // -0.0 -> +0.0
    bts = (bts & 0x80000000u) ? ~bts : (bts | 0x80000000u);
    return ((u64)bts << 32) | (unsigned int)q;
}

__device__ __forceinline__ u64 umin64(u64 a, u64 b) { return a < b ? a : b; }
__device__ __forceinline__ u64 umax64(u64 a, u64 b) { return a > b ? a : b; }

// branchless bubble-insert of c into asc-sorted 5-list (keep 5 smallest)
__device__ __forceinline__ void ins5_asc(u64& k0, u64& k1, u64& k2, u64& k3, u64& k4, u64 c) {
    u64 n;
    n = umin64(k0, c); c = umax64(k0, c); k0 = n;
    n = umin64(k1, c); c = umax64(k1, c); k1 = n;
    n = umin64(k2, c); c = umax64(k2, c); k2 = n;
    n = umin64(k3, c); c = umax64(k3, c); k3 = n;
    k4 = umin64(k4, c);
}

// branchless bubble-insert of c into desc-sorted 5-list (keep 5 largest)
__device__ __forceinline__ void ins5_desc(float& t0, float& t1, float& t2, float& t3, float& t4, float c) {
    float n;
    n = fmaxf(t0, c); c = fminf(t0, c); t0 = n;
    n = fmaxf(t1, c); c = fminf(t1, c); t1 = n;
    n = fmaxf(t2, c); c = fminf(t2, c); t2 = n;
    n = fmaxf(t3, c); c = fminf(t3, c); t3 = n;
    t4 = fmaxf(t4, c);
}

// merge two desc-sorted 5-lists -> top-5 desc (branchless network)
__device__ __forceinline__ void merge5_desc(
    float& a0, float& a1, float& a2, float& a3, float& a4,
    float b0, float b1, float b2, float b3, float b4)
{
    const float r0 = fmaxf(a0, b0);
    const float r1 = fmaxf(fmaxf(a1, b1), fminf(a0, b0));
    const float r2 = fmaxf(fmaxf(a2, b2), fmaxf(fminf(a0, b1), fminf(a1, b0)));
    const float r3 = fmaxf(fmaxf(a3, b3),
                     fmaxf(fminf(a0, b2), fmaxf(fminf(a1, b1), fminf(a2, b0))));
    const float r4 = fmaxf(fmaxf(a4, b4),
                     fmaxf(fmaxf(fminf(a0, b3), fminf(a3, b0)),
                           fmaxf(fminf(a1, b2), fminf(a2, b1))));
    a0 = r0; a1 = r1; a2 = r2; a3 = r3; a4 = r4;
}

// merge two asc-sorted 5-lists of u64 keys -> bottom-5 asc
__device__ __forceinline__ void merge5_asc(
    u64& a0, u64& a1, u64& a2, u64& a3, u64& a4,
    u64 b0, u64 b1, u64 b2, u64 b3, u64 b4)
{
    const u64 r0 = umin64(a0, b0);
    const u64 r1 = umin64(umin64(a1, b1), umax64(a0, b0));
    const u64 r2 = umin64(umin64(a2, b2), umin64(umax64(a0, b1), umax64(a1, b0)));
    const u64 r3 = umin64(umin64(a3, b3),
                   umin64(umax64(a0, b2), umin64(umax64(a1, b1), umax64(a2, b0))));
    const u64 r4 = umin64(umin64(a4, b4),
                   umin64(umin64(umax64(a0, b3), umax64(a3, b0)),
                          umin64(umax64(a1, b2), umax64(a2, b1))));
    a0 = r0; a1 = r1; a2 = r2; a3 = r3; a4 = r4;
}

__device__ __forceinline__ float focal_cost(float x) {
    float p;
    if (x >= 0.f) { const float e = expf(-x); p = 1.f / (1.f + e); }
    else          { const float e = expf(x);  p = e / (1.f + e); }
    const float pos = 0.25f * (1.f - p) * (1.f - p) * (-logf(p + 1e-8f));
    const float neg = 0.75f * p * p * (-logf(1.f - p + 1e-8f));
    return pos - neg;
}

// ---------------------------------------------------------------------------
// Kernel A: fused cost/iou + focal (in-LDS) + per-chunk top-5 iou AND
// bottom-5 cost partials (branchless, dual-list) + row-argmin + coalesced
// costT via tile.  Block = (chunk of 16 q's, batch); g = tid&127, qh = tid>>7.
// ---------------------------------------------------------------------------
__global__ __launch_bounds__(256) void fused_cost_kernel(
    const float* __restrict__ logits,
    const float* __restrict__ pboxes,
    const float* __restrict__ gboxes,
    const int*   __restrict__ glabels,
    float* __restrict__ out_cost,
    float* __restrict__ out_iou,
    float* __restrict__ costT,
    float* __restrict__ piou,
    u64*   __restrict__ pcost,
    int*   __restrict__ ramin)
{
    const int tid = threadIdx.x;
    const int g   = tid & 127;
    const int qh  = tid >> 7;
    const int ci  = blockIdx.x, b = blockIdx.y;
    const int q0  = ci * QCHUNK;

    __shared__ float pq[QCHUNK][16];
    __shared__ int   fgf[QCHUNK];
    __shared__ __align__(16) char lk_buf[5120];  // lbuf float[1280] -> khalf u64[128][5]
    __shared__ float ctile[QCHUNK][G_ + 1];
    __shared__ float phalf[G_][5];
    float* lbuf = (float*)lk_buf;
    u64 (*khalf)[5] = (u64(*)[5])lk_buf;

    // ---- per-thread gt constants ----
    const float4* gb4 = (const float4*)(gboxes + ((size_t)b * G_ + g) * 8);
    const float4 gA = gb4[0], gB = gb4[1];
    const float g0 = gA.x, g1 = gA.y, g2 = gA.z, g3 = gA.w;
    const float g4 = gB.x, g5 = gB.y, g6 = gB.z, g7 = gB.w;
    const float gxc = (g0 + g2 + g4 + g6) * 0.25f;
    const float gyc = (g1 + g3 + g5 + g7) * 0.25f;
    const float gw = sqrtf((g0 - g2) * (g0 - g2) + (g1 - g3) * (g1 - g3));
    const float gh = sqrtf((g2 - g4) * (g2 - g4) + (g3 - g5) * (g3 - g5));
    const float gax0 = gxc - gw * 0.5f, gay0 = gyc - gh * 0.5f;
    const float gax1 = gxc + gw * 0.5f, gay1 = gyc + gh * 0.5f;
    const float garea = (gax1 - gax0) * (gay1 - gay0);
    const float v1x = g2 - g0, v1y = g3 - g1, v2x = g4 - g0, v2y = g5 - g1;
    const float gt_area = fabsf(v1x * v2y - v1y * v2x) * 0.5f;
    const float mxx = fmaxf(fmaxf(g0, g2), fmaxf(g4, g6));
    const float mnx = fminf(fminf(g0, g2), fminf(g4, g6));
    const float mxy = fmaxf(fmaxf(g1, g3), fmaxf(g5, g7));
    const float mny = fminf(fminf(g1, g3), fminf(g5, g7));
    const float dgx = mxx - mnx, dgy = mxy - mny;
    const float radius = sqrtf(dgx * dgx + dgy * dgy) / 32.0f;
    const float thresh = gt_area / radius;
    const int lab = glabels[b * G_ + g];

    // ---- stage pred boxes (16 q x 8 floats = 32 float4) ----
    if (tid < 32) {
        const float4 v = ((const float4*)(pboxes + ((size_t)b * Q_ + q0) * 8))[tid];
        *(float4*)&pq[tid >> 1][(tid & 1) * 4] = v;
    }
    __syncthreads();
    if (tid < QCHUNK) {
        const float* pr = pq[tid];
        const float p0 = pr[0], p1 = pr[1], p2 = pr[2], p3 = pr[3];
        const float p4 = pr[4], p5v = pr[5], p6 = pr[6], p7 = pr[7];
        const float pxc = (p0 + p2 + p4 + p6) * 0.25f;
        const float pyc = (p1 + p3 + p5v + p7) * 0.25f;
        const float pw = sqrtf((p0 - p2) * (p0 - p2) + (p1 - p3) * (p1 - p3));
        const float ph = sqrtf((p2 - p4) * (p2 - p4) + (p3 - p5v) * (p3 - p5v));
        pq[tid][8]  = pxc;
        pq[tid][9]  = pyc;
        pq[tid][10] = pxc - pw * 0.5f;
        pq[tid][11] = pyc - ph * 0.5f;
        pq[tid][12] = pxc + pw * 0.5f;
        pq[tid][13] = pyc + ph * 0.5f;
        pq[tid][14] = pw * ph;
        fgf[tid] = 0;
    }
    // focal class-cost table for this chunk (16 q x 80 classes)
    __syncthreads();
    for (int j = tid; j < QCHUNK * 80; j += 256)
        lbuf[j] = focal_cost(logits[((size_t)b * Q_ + q0) * 80 + j]);

    // ---- fg mask (any over g); fgf written by lane0 of each wave ----
    const int lane0 = ((tid & 63) == 0);
    for (int i = 0; i < QCHUNK / 2; ++i) {
        const int ql = 2 * i + qh;
        const float dx = pq[ql][8] - gxc, dy = pq[ql][9] - gyc;
        const int in = sqrtf(dx * dx + dy * dy) <= thresh;
        const int anyin = __any(in);
        if (anyin && lane0) fgf[ql] = 1;
    }
    __syncthreads();

    // ---- main loop: dual branchless lists (A: jj 0-3, B: jj 4-7) ----
    float ta0 = -1e38f, ta1 = -1e38f, ta2 = -1e38f, ta3 = -1e38f, ta4 = -1e38f;
    float tb0 = -1e38f, tb1 = -1e38f, tb2 = -1e38f, tb3 = -1e38f, tb4 = -1e38f;
    u64 ka0 = U64MAX, ka1 = U64MAX, ka2 = U64MAX, ka3 = U64MAX, ka4 = U64MAX;
    u64 kb0 = U64MAX, kb1 = U64MAX, kb2 = U64MAX, kb3 = U64MAX, kb4 = U64MAX;

    float* pc = out_cost + ((size_t)b * Q_ + q0 + qh) * G_ + g;
    float* pi = out_iou  + ((size_t)b * Q_ + q0 + qh) * G_ + g;

    #pragma unroll
    for (int jj = 0; jj < 8; ++jj) {
        const int qls = 2 * jj + qh;       // 0..15
        const int q   = q0 + qls;
        const float4 prA = *(const float4*)&pq[qls][0];
        const float4 prB = *(const float4*)&pq[qls][4];
        const float4 prC = *(const float4*)&pq[qls][8];
        const float4 prD = *(const float4*)&pq[qls][12];
        const float p0 = prA.x, p1 = prA.y, p2 = prA.z, p3 = prA.w;
        const float p4 = prB.x, p5v = prB.y, p6 = prB.z, p7 = prB.w;
        const float pxc = prC.x, pyc = prC.y;
        const float pax0 = prC.z, pay0 = prC.w, pax1 = prD.x, pay1 = prD.y;
        const float parea = prD.z;

        const float l1 = fabsf(p0 - g0) + fabsf(p1 - g1) + fabsf(p2 - g2)
                       + fabsf(p3 - g3) + fabsf(p4 - g4) + fabsf(p5v - g5)
                       + fabsf(p6 - g6) + fabsf(p7 - g7);

        const float ltx = fmaxf(pax0, gax0), lty = fmaxf(pay0, gay0);
        const float rbx = fminf(pax1, gax1), rby = fminf(pay1, gay1);
        const float iw = fmaxf(rbx - ltx, 0.f), ih = fmaxf(rby - lty, 0.f);
        const float inter = iw * ih;
        const float iou = inter / (parea + garea - inter + 1e-8f);

        const float ew = fmaxf(pax1, gax1) - fminf(pax0, gax0);
        const float eh = fmaxf(pay1, gay1) - fminf(pay0, gay0);
        const float cc2 = ew * ew + eh * eh + 1e-8f;
        const float dx = pxc - gxc, dy = pyc - gyc;
        const float diou = iou - (dx * dx + dy * dy) / cc2;

        const float cclass = lbuf[qls * 80 + lab];
        const float cost = 5.f * l1 + 2.f * cclass + 2.f * diou
                         + (fgf[qls] ? 0.f : 10000.f);

        *pc = cost; pc += 2 * G_;
        *pi = iou;  pi += 2 * G_;
        ctile[qls][g] = cost;

        const u64 kk = packkey(cost, q);
        if (jj < 4) {
            ins5_desc(ta0, ta1, ta2, ta3, ta4, iou);
            ins5_asc(ka0, ka1, ka2, ka3, ka4, kk);
        } else {
            ins5_desc(tb0, tb1, tb2, tb3, tb4, iou);
            ins5_asc(kb0, kb1, kb2, kb3, kb4, kk);
        }
    }
    // merge dual lists
    merge5_desc(ta0, ta1, ta2, ta3, ta4, tb0, tb1, tb2, tb3, tb4);
    merge5_asc(ka0, ka1, ka2, ka3, ka4, kb0, kb1, kb2, kb3, kb4);

    __syncthreads();   // ctile complete; lbuf reads done (khalf may overlay)

    // ---- coalesced costT writeout from LDS tile (16 q x 128 g) ----
    for (int t = tid; t < QCHUNK * G_ / 4; t += 256) {
        const int gg = t >> 2;          // 4 float4 (of q) per g
        const int k  = (t & 3) << 2;
        float4 o;
        o.x = ctile[k + 0][gg]; o.y = ctile[k + 1][gg];
        o.z = ctile[k + 2][gg]; o.w = ctile[k + 3][gg];
        *(float4*)&costT[((size_t)b * G_ + gg) * Q_ + q0 + k] = o;
    }

    // ---- in-kernel row argmin (first-index tie-break), 16 lanes per q ----
    {
        const int qls  = tid >> 4;      // 0..15
        const int part = tid & 15;
        float v = 1e38f; int mg = 0x7fffffff;
        #pragma unroll
        for (int j = 0; j < 8; ++j) {
            const int gg = part + 16 * j;
            const float c = ctile[qls][gg];
            if (c < v || (c == v && gg < mg)) { v = c; mg = gg; }
        }
        #pragma unroll
        for (int off = 1; off < 16; off <<= 1) {
            const float ov = __shfl_xor(v, off);
            const int   og = __shfl_xor(mg, off);
            if (ov < v || (ov == v && og < mg)) { v = ov; mg = og; }
        }
        if (part == 0) ramin[b * Q_ + q0 + qls] = mg;
    }

    // ---- merge q-halves of both partial lists, write per (b, chunk, g) ----
    if (qh == 1) {
        phalf[g][0] = ta0; phalf[g][1] = ta1; phalf[g][2] = ta2;
        phalf[g][3] = ta3; phalf[g][4] = ta4;
        khalf[g][0] = ka0; khalf[g][1] = ka1; khalf[g][2] = ka2;
        khalf[g][3] = ka3; khalf[g][4] = ka4;
    }
    __syncthreads();
    if (qh == 0) {
        merge5_desc(ta0, ta1, ta2, ta3, ta4,
                    phalf[g][0], phalf[g][1], phalf[g][2], phalf[g][3], phalf[g][4]);
        merge5_asc(ka0, ka1, ka2, ka3, ka4,
                   khalf[g][0], khalf[g][1], khalf[g][2], khalf[g][3], khalf[g][4]);
        // coalesced layout: [B][NCH][G][5]
        const size_t pbase = (((size_t)b * NCH + ci) * G_ + g) * 5;
        piou[pbase + 0] = ta0; piou[pbase + 1] = ta1; piou[pbase + 2] = ta2;
        piou[pbase + 3] = ta3; piou[pbase + 4] = ta4;
        pcost[pbase + 0] = ka0; pcost[pbase + 1] = ka1; pcost[pbase + 2] = ka2;
        pcost[pbase + 3] = ka3; pcost[pbase + 4] = ka4;
    }
}

// ---------------------------------------------------------------------------
// Kernel B: per-column (block=256 = one thread per chunk-list): merge 256
// sorted 5-lists (cost keys asc, iou desc) -> cand, dyn_k, scatter.
// ---------------------------------------------------------------------------
__global__ __launch_bounds__(256) void dynk_scatter_kernel(
    const u64*   __restrict__ pcost,
    const float* __restrict__ piou,
    u64* __restrict__ cand,
    int* __restrict__ cnt,
    int* __restrict__ gsel)
{
    const int col = blockIdx.x;          // b*G + g
    const int b = col >> 7, g = col & 127;
    const int tid = threadIdx.x;         // = chunk index ci
    const int wv = tid >> 6, ln = tid & 63;

    __shared__ u64   wl[4][5];
    __shared__ float il[4][5];

    // layout [B][NCH][G][5]
    const size_t base = (((size_t)b * NCH + tid) * G_ + g) * 5;

    u64 k0 = pcost[base + 0], k1 = pcost[base + 1], k2 = pcost[base + 2],
        k3 = pcost[base + 3], k4 = pcost[base + 4];
    float t0 = piou[base + 0], t1 = piou[base + 1], t2 = piou[base + 2],
          t3 = piou[base + 3], t4 = piou[base + 4];

    #pragma unroll
    for (int off = 1; off < 64; off <<= 1) {
        merge5_asc(k0, k1, k2, k3, k4,
                   __shfl_xor(k0, off), __shfl_xor(k1, off), __shfl_xor(k2, off),
                   __shfl_xor(k3, off), __shfl_xor(k4, off));
        merge5_desc(t0, t1, t2, t3, t4,
                    __shfl_xor(t0, off), __shfl_xor(t1, off), __shfl_xor(t2, off),
                    __shfl_xor(t3, off), __shfl_xor(t4, off));
    }
    if (ln == 0) {
        wl[wv][0] = k0; wl[wv][1] = k1; wl[wv][2] = k2; wl[wv][3] = k3; wl[wv][4] = k4;
        il[wv][0] = t0; il[wv][1] = t1; il[wv][2] = t2; il[wv][3] = t3; il[wv][4] = t4;
    }
    __syncthreads();

    if (tid == 0) {
        u64 f0 = wl[0][0], f1 = wl[0][1], f2 = wl[0][2], f3 = wl[0][3], f4 = wl[0][4];
        merge5_asc(f0, f1, f2, f3, f4, wl[1][0], wl[1][1], wl[1][2], wl[1][3], wl[1][4]);
        merge5_asc(f0, f1, f2, f3, f4, wl[2][0], wl[2][1], wl[2][2], wl[2][3], wl[2][4]);
        merge5_asc(f0, f1, f2, f3, f4, wl[3][0], wl[3][1], wl[3][2], wl[3][3], wl[3][4]);
        float s0 = il[0][0], s1 = il[0][1], s2 = il[0][2], s3 = il[0][3], s4 = il[0][4];
        merge5_desc(s0, s1, s2, s3, s4, il[1][0], il[1][1], il[1][2], il[1][3], il[1][4]);
        merge5_desc(s0, s1, s2, s3, s4, il[2][0], il[2][1], il[2][2], il[2][3], il[2][4]);
        merge5_desc(s0, s1, s2, s3, s4, il[3][0], il[3][1], il[3][2], il[3][3], il[3][4]);

        cand[(size_t)col * 5 + 0] = f0;
        cand[(size_t)col * 5 + 1] = f1;
        cand[(size_t)col * 5 + 2] = f2;
        cand[(size_t)col * 5 + 3] = f3;
        cand[(size_t)col * 5 + 4] = f4;

        const float s = s0 + s1 + s2 + s3 + s4;
        int dynk = (int)s;
        if (dynk < 1) dynk = 1;
        if (dynk > 5) dynk = 5;
        const u64 ks[5] = {f0, f1, f2, f3, f4};
        #pragma unroll
        for (int i = 0; i < 5; ++i) {
            if (i < dynk) {
                const int q = (int)(ks[i] & 0xffffffffu);
                atomicAdd(&cnt[b * Q_ + q], 1);
                gsel[b * Q_ + q] = g;   // only read when cnt==1
            }
        }
    }
}

// ---------------------------------------------------------------------------
// Kernel C: per-batch event-driven refinement loop (1024 threads).
// Hits only land on unmatched rows; rows never re-assign; columns never
// unmatch.  Wave-parallel fallback refills a column's candidate list with
// the bottom-5 currently-unmatched rows (prefix-validity argument).
// ---------------------------------------------------------------------------
__global__ __launch_bounds__(1024) void loop_kernel(
    const float* __restrict__ costT,
    const int* __restrict__ cnt,
    const int* __restrict__ gsel,
    const int* __restrict__ ramin,
    const u64* __restrict__ cand,
    int* __restrict__ rmatch_final)
{
    const int b = blockIdx.x, tid = threadIdx.x;
    const int wv = tid >> 6, ln = tid & 63;

    __shared__ short rmatch[Q_];            // 8 KB
    __shared__ unsigned char s_ra[Q_];      // 4 KB
    __shared__ int newh[Q_];                // 16 KB
    __shared__ unsigned char newg[Q_];      // 4 KB
    __shared__ u64 scand[G_][5];            // 5 KB
    __shared__ int ptrs[G_], col_cnt[G_], unm_list[G_], prop[G_], fb_slot[G_], touched[G_];
    __shared__ int n_unm, n_fb, n_touch;

    for (int q = tid; q < Q_; q += 1024) {
        const int c  = cnt[b * Q_ + q];
        const int ra = ramin[b * Q_ + q];
        s_ra[q] = (unsigned char)ra;
        newh[q] = 0;
        rmatch[q] = (c == 0) ? (short)-1
                             : (c == 1 ? (short)gsel[b * Q_ + q] : (short)ra);
    }
    if (tid < G_) { col_cnt[tid] = 0; ptrs[tid] = 0; }
    if (tid < G_ * 5)
        scand[tid / 5][tid % 5] = cand[(size_t)b * G_ * 5 + tid];
    __syncthreads();
    for (int q = tid; q < Q_; q += 1024)
        if (rmatch[q] >= 0) atomicAdd(&col_cnt[rmatch[q]], 1);
    __syncthreads();

    for (int it = 0; it < G_; ++it) {
        if (tid == 0) { n_unm = 0; n_fb = 0; n_touch = 0; }
        __syncthreads();
        if (tid < G_ && col_cnt[tid] == 0)
            unm_list[atomicAdd(&n_unm, 1)] = tid;
        __syncthreads();
        const int nu = n_unm;
        if (nu == 0) break;

        // propose: first unmatched candidate, else mark for fallback scan
        if (tid < nu) {
            const int g = unm_list[tid];
            int p = ptrs[g];
            int q = -1;
            while (p < 5) {
                const int cq = (int)(scand[g][p] & 0xffffffffu);
                if (rmatch[cq] < 0) { q = cq; break; }
                ++p;
            }
            ptrs[g] = p;
            prop[tid] = q;
            if (q < 0) fb_slot[atomicAdd(&n_fb, 1)] = tid;
        }
        __syncthreads();

        // wave-parallel fallback (16 waves): bottom-5 unmatched + refill
        const int nf = n_fb;
        for (int i = wv; i < nf; i += 16) {
            const int slot = fb_slot[i];
            const int g = unm_list[slot];
            const float4* colp = (const float4*)(costT + ((size_t)b * G_ + g) * Q_);
            u64 k0 = U64MAX, k1 = U64MAX, k2 = U64MAX, k3 = U64MAX, k4 = U64MAX;
            #pragma unroll 4
            for (int s = 0; s < Q_ / 256; ++s) {
                const int idx = ln + s * 64;
                const float4 c4 = colp[idx];
                const int qb = idx * 4;
                const float vv[4] = {c4.x, c4.y, c4.z, c4.w};
                #pragma unroll
                for (int j = 0; j < 4; ++j) {
                    if (rmatch[qb + j] < 0)
                        ins5_asc(k0, k1, k2, k3, k4, packkey(vv[j], qb + j));
                }
            }
            #pragma unroll
            for (int off = 1; off < 64; off <<= 1) {
                merge5_asc(k0, k1, k2, k3, k4,
                           __shfl_xor(k0, off), __shfl_xor(k1, off), __shfl_xor(k2, off),
                           __shfl_xor(k3, off), __shfl_xor(k4, off));
            }
            if (ln == 0) {
                scand[g][0] = k0; scand[g][1] = k1; scand[g][2] = k2;
                scand[g][3] = k3; scand[g][4] = k4;
                ptrs[g] = 0;
                prop[slot] = (int)(k0 & 0xffffffffu);
            }
        }
        __syncthreads();

        // hits
        if (tid < nu) {
            const int q = prop[tid];
            newg[q] = (unsigned char)unm_list[tid];  // consumed only when nh==1
            if (atomicAdd(&newh[q], 1) == 0)
                touched[atomicAdd(&n_touch, 1)] = q;
        }
        __syncthreads();

        // resolve (dedup): hits only land on unmatched rows
        const int nt = n_touch;
        if (tid < nt) {
            const int q = touched[tid];
            const int nh = newh[q];
            const int gg = (nh == 1) ? (int)newg[q] : (int)s_ra[q];
            rmatch[q] = (short)gg;
            atomicAdd(&col_cnt[gg], 1);
            newh[q] = 0;
        }
        __syncthreads();
    }

    for (int q = tid; q < Q_; q += 1024)
        rmatch_final[b * Q_ + q] = rmatch[q];
}

// ---------------------------------------------------------------------------
// Kernel D: expand rmatch -> full match plane (fully parallel float4 writes).
// ---------------------------------------------------------------------------
__global__ __launch_bounds__(256) void expand_kernel(
    const int* __restrict__ rmatch_final, float* __restrict__ out_match)
{
    const int idx = blockIdx.x * 256 + threadIdx.x;  // float4 index
    const int row = idx >> 5;                        // G/4 = 32 float4 per row
    const int gb  = (idx & 31) << 2;
    const int rm  = rmatch_final[row];
    float4 o;
    o.x = (rm == gb)     ? 1.f : 0.f;
    o.y = (rm == gb + 1) ? 1.f : 0.f;
    o.z = (rm == gb + 2) ? 1.f : 0.f;
    o.w = (rm == gb + 3) ? 1.f : 0.f;
    ((float4*)out_match)[idx] = o;
}

extern "C" void kernel_launch(void* const* d_in, const int* in_sizes, int n_in,
                              void* d_out, int out_size, void* d_ws, size_t ws_size,
                              hipStream_t stream) {
    const float* logits  = (const float*)d_in[0];
    const float* pboxes  = (const float*)d_in[1];
    const float* gboxes  = (const float*)d_in[2];
    const int*   glabels = (const int*)d_in[3];

    float* out = (float*)d_out;
    const size_t BQG = (size_t)B_ * Q_ * G_;
    float* out_match = out;
    float* out_cost  = out + BQG;
    float* out_iou   = out + 2 * BQG;

    // workspace layout (~66 MB)
    char* ws = (char*)d_ws;
    size_t off = 0;
    float* costT  = (float*)(ws + off); off += (size_t)B_ * G_ * Q_ * 4;
    u64*   pcost  = (u64*)  (ws + off); off += (size_t)B_ * G_ * NCH * 5 * 8;
    float* piou   = (float*)(ws + off); off += (size_t)B_ * G_ * NCH * 5 * 4;
    u64*   cand   = (u64*)  (ws + off); off += (size_t)B_ * G_ * 5 * 8;
    int*   ramin  = (int*)  (ws + off); off += (size_t)B_ * Q_ * 4;
    int*   cnt    = (int*)  (ws + off); off += (size_t)B_ * Q_ * 4;
    int*   gsel   = (int*)  (ws + off); off += (size_t)B_ * Q_ * 4;
    int*   rmf    = (int*)  (ws + off); off += (size_t)B_ * Q_ * 4;

    hipMemsetAsync(cnt, 0, (size_t)B_ * Q_ * 4, stream);
    fused_cost_kernel<<<dim3(NCH, B_), 256, 0, stream>>>(
        logits, pboxes, gboxes, glabels, out_cost, out_iou, costT, piou, pcost, ramin);
    dynk_scatter_kernel<<<B_ * G_, 256, 0, stream>>>(pcost, piou, cand, cnt, gsel);
    loop_kernel<<<B_, 1024, 0, stream>>>(costT, cnt, gsel, ramin, cand, rmf);
    expand_kernel<<<(int)(BQG / 4 / 256), 256, 0, stream>>>(rmf, out_match);
}

// Round 9
// 196.158 us; speedup vs baseline: 1.0982x; 1.0982x over previous
//
#include <hip/hip_runtime.h>
#include <cstdint>
#include <cstddef>

#define B_ 16
#define Q_ 4096
#define G_ 128
#define C_ 80
#define QCHUNK 16
#define NCH (Q_ / QCHUNK)   // 256 chunks

typedef unsigned long long u64;
#define U64MAX 0xffffffffffffffffull

// pack (cost,q) into a sortable u64 key: asc key order == lex (cost asc, q asc)
__device__ __forceinline__ u64 packkey(float v, int q) {
    unsigned int bts = __float_as_uint(v);
    if (bts == 0x80000000u) bts = 0u;  // -0.0 -> +0.0
    bts = (bts & 0x80000000u) ? ~bts : (bts | 0x80000000u);
    return ((u64)bts << 32) | (unsigned int)q;
}

__device__ __forceinline__ u64 umin64(u64 a, u64 b) { return a < b ? a : b; }
__device__ __forceinline__ u64 umax64(u64 a, u64 b) { return a > b ? a : b; }

// merge two desc-sorted 5-lists -> top-5 desc (branchless network)
__device__ __forceinline__ void merge5_desc(
    float& a0, float& a1, float& a2, float& a3, float& a4,
    float b0, float b1, float b2, float b3, float b4)
{
    const float r0 = fmaxf(a0, b0);
    const float r1 = fmaxf(fmaxf(a1, b1), fminf(a0, b0));
    const float r2 = fmaxf(fmaxf(a2, b2), fmaxf(fminf(a0, b1), fminf(a1, b0)));
    const float r3 = fmaxf(fmaxf(a3, b3),
                     fmaxf(fminf(a0, b2), fmaxf(fminf(a1, b1), fminf(a2, b0))));
    const float r4 = fmaxf(fmaxf(a4, b4),
                     fmaxf(fmaxf(fminf(a0, b3), fminf(a3, b0)),
                           fmaxf(fminf(a1, b2), fminf(a2, b1))));
    a0 = r0; a1 = r1; a2 = r2; a3 = r3; a4 = r4;
}

// merge two asc-sorted 5-lists of u64 keys -> bottom-5 asc
__device__ __forceinline__ void merge5_asc(
    u64& a0, u64& a1, u64& a2, u64& a3, u64& a4,
    u64 b0, u64 b1, u64 b2, u64 b3, u64 b4)
{
    const u64 r0 = umin64(a0, b0);
    const u64 r1 = umin64(umin64(a1, b1), umax64(a0, b0));
    const u64 r2 = umin64(umin64(a2, b2), umin64(umax64(a0, b1), umax64(a1, b0)));
    const u64 r3 = umin64(umin64(a3, b3),
                   umin64(umax64(a0, b2), umin64(umax64(a1, b1), umax64(a2, b0))));
    const u64 r4 = umin64(umin64(a4, b4),
                   umin64(umin64(umax64(a0, b3), umax64(a3, b0)),
                          umin64(umax64(a1, b2), umax64(a2, b1))));
    a0 = r0; a1 = r1; a2 = r2; a3 = r3; a4 = r4;
}

__device__ __forceinline__ float focal_cost(float x) {
    float p;
    if (x >= 0.f) { const float e = expf(-x); p = 1.f / (1.f + e); }
    else          { const float e = expf(x);  p = e / (1.f + e); }
    const float pos = 0.25f * (1.f - p) * (1.f - p) * (-logf(p + 1e-8f));
    const float neg = 0.75f * p * p * (-logf(1.f - p + 1e-8f));
    return pos - neg;
}

// ---------------------------------------------------------------------------
// Kernel A: fused cost/iou + focal (in-LDS) + per-chunk top-5 iou AND
// bottom-5 cost partials (branchy early-exit: low VGPR) + row-argmin.
// No costT copy.  Block = (chunk of 16 q's, batch); g = tid&127, qh = tid>>7.
// Also zeroes cnt (each (b,q) covered exactly once).
// ---------------------------------------------------------------------------
__global__ __launch_bounds__(256) void fused_cost_kernel(
    const float* __restrict__ logits,
    const float* __restrict__ pboxes,
    const float* __restrict__ gboxes,
    const int*   __restrict__ glabels,
    float* __restrict__ out_cost,
    float* __restrict__ out_iou,
    float* __restrict__ piou,
    u64*   __restrict__ pcost,
    int*   __restrict__ ramin,
    int*   __restrict__ cnt)
{
    const int tid = threadIdx.x;
    const int g   = tid & 127;
    const int qh  = tid >> 7;
    const int ci  = blockIdx.x, b = blockIdx.y;
    const int q0  = ci * QCHUNK;

    __shared__ float pq[QCHUNK][16];
    __shared__ int   fgf[QCHUNK];
    __shared__ __align__(16) char lk_buf[5120];  // lbuf float[1280] -> khalf u64[128][5]
    __shared__ float ctile[QCHUNK][G_ + 1];
    __shared__ float phalf[G_][5];
    float* lbuf = (float*)lk_buf;
    u64 (*khalf)[5] = (u64(*)[5])lk_buf;

    // zero cnt for this block's 16 q's (consumed by dynk after fused completes)
    if (tid < QCHUNK) cnt[b * Q_ + q0 + tid] = 0;

    // ---- per-thread gt constants ----
    const float4* gb4 = (const float4*)(gboxes + ((size_t)b * G_ + g) * 8);
    const float4 gA = gb4[0], gB = gb4[1];
    const float g0 = gA.x, g1 = gA.y, g2 = gA.z, g3 = gA.w;
    const float g4 = gB.x, g5 = gB.y, g6 = gB.z, g7 = gB.w;
    const float gxc = (g0 + g2 + g4 + g6) * 0.25f;
    const float gyc = (g1 + g3 + g5 + g7) * 0.25f;
    const float gw = sqrtf((g0 - g2) * (g0 - g2) + (g1 - g3) * (g1 - g3));
    const float gh = sqrtf((g2 - g4) * (g2 - g4) + (g3 - g5) * (g3 - g5));
    const float gax0 = gxc - gw * 0.5f, gay0 = gyc - gh * 0.5f;
    const float gax1 = gxc + gw * 0.5f, gay1 = gyc + gh * 0.5f;
    const float garea = (gax1 - gax0) * (gay1 - gay0);
    const float v1x = g2 - g0, v1y = g3 - g1, v2x = g4 - g0, v2y = g5 - g1;
    const float gt_area = fabsf(v1x * v2y - v1y * v2x) * 0.5f;
    const float mxx = fmaxf(fmaxf(g0, g2), fmaxf(g4, g6));
    const float mnx = fminf(fminf(g0, g2), fminf(g4, g6));
    const float mxy = fmaxf(fmaxf(g1, g3), fmaxf(g5, g7));
    const float mny = fminf(fminf(g1, g3), fminf(g5, g7));
    const float dgx = mxx - mnx, dgy = mxy - mny;
    const float radius = sqrtf(dgx * dgx + dgy * dgy) / 32.0f;
    const float thresh = gt_area / radius;
    const int lab = glabels[b * G_ + g];

    // ---- stage pred boxes (16 q x 8 floats = 32 float4) ----
    if (tid < 32) {
        const float4 v = ((const float4*)(pboxes + ((size_t)b * Q_ + q0) * 8))[tid];
        *(float4*)&pq[tid >> 1][(tid & 1) * 4] = v;
    }
    __syncthreads();
    if (tid < QCHUNK) {
        const float* pr = pq[tid];
        const float p0 = pr[0], p1 = pr[1], p2 = pr[2], p3 = pr[3];
        const float p4 = pr[4], p5v = pr[5], p6 = pr[6], p7 = pr[7];
        const float pxc = (p0 + p2 + p4 + p6) * 0.25f;
        const float pyc = (p1 + p3 + p5v + p7) * 0.25f;
        const float pw = sqrtf((p0 - p2) * (p0 - p2) + (p1 - p3) * (p1 - p3));
        const float ph = sqrtf((p2 - p4) * (p2 - p4) + (p3 - p5v) * (p3 - p5v));
        pq[tid][8]  = pxc;
        pq[tid][9]  = pyc;
        pq[tid][10] = pxc - pw * 0.5f;
        pq[tid][11] = pyc - ph * 0.5f;
        pq[tid][12] = pxc + pw * 0.5f;
        pq[tid][13] = pyc + ph * 0.5f;
        pq[tid][14] = pw * ph;
        fgf[tid] = 0;
    }
    // focal class-cost table for this chunk (16 q x 80 classes)
    __syncthreads();
    for (int j = tid; j < QCHUNK * 80; j += 256)
        lbuf[j] = focal_cost(logits[((size_t)b * Q_ + q0) * 80 + j]);

    // ---- fg mask (any over g); fgf written by lane0 of each wave ----
    const int lane0 = ((tid & 63) == 0);
    for (int i = 0; i < QCHUNK / 2; ++i) {
        const int ql = 2 * i + qh;
        const float dx = pq[ql][8] - gxc, dy = pq[ql][9] - gyc;
        const int in = sqrtf(dx * dx + dy * dy) <= thresh;
        const int anyin = __any(in);
        if (anyin && lane0) fgf[ql] = 1;
    }
    __syncthreads();

    // ---- main loop: full cost + running top-5 iou + bottom-5 cost keys ----
    float t0 = -1e38f, t1 = -1e38f, t2 = -1e38f, t3 = -1e38f, t4 = -1e38f;
    u64 k0 = U64MAX, k1 = U64MAX, k2 = U64MAX, k3 = U64MAX, k4 = U64MAX;

    #pragma unroll
    for (int jj = 0; jj < 8; ++jj) {
        const int qls = 2 * jj + qh;       // 0..15
        const int q   = q0 + qls;
        const float4 prA = *(const float4*)&pq[qls][0];
        const float4 prB = *(const float4*)&pq[qls][4];
        const float4 prC = *(const float4*)&pq[qls][8];
        const float4 prD = *(const float4*)&pq[qls][12];
        const float p0 = prA.x, p1 = prA.y, p2 = prA.z, p3 = prA.w;
        const float p4 = prB.x, p5v = prB.y, p6 = prB.z, p7 = prB.w;
        const float pxc = prC.x, pyc = prC.y;
        const float pax0 = prC.z, pay0 = prC.w, pax1 = prD.x, pay1 = prD.y;
        const float parea = prD.z;

        const float l1 = fabsf(p0 - g0) + fabsf(p1 - g1) + fabsf(p2 - g2)
                       + fabsf(p3 - g3) + fabsf(p4 - g4) + fabsf(p5v - g5)
                       + fabsf(p6 - g6) + fabsf(p7 - g7);

        const float ltx = fmaxf(pax0, gax0), lty = fmaxf(pay0, gay0);
        const float rbx = fminf(pax1, gax1), rby = fminf(pay1, gay1);
        const float iw = fmaxf(rbx - ltx, 0.f), ih = fmaxf(rby - lty, 0.f);
        const float inter = iw * ih;
        const float iou = inter / (parea + garea - inter + 1e-8f);

        const float ew = fmaxf(pax1, gax1) - fminf(pax0, gax0);
        const float eh = fmaxf(pay1, gay1) - fminf(pay0, gay0);
        const float cc2 = ew * ew + eh * eh + 1e-8f;
        const float dx = pxc - gxc, dy = pyc - gyc;
        const float diou = iou - (dx * dx + dy * dy) / cc2;

        const float cclass = lbuf[qls * 80 + lab];
        const float cost = 5.f * l1 + 2.f * cclass + 2.f * diou
                         + (fgf[qls] ? 0.f : 10000.f);

        const size_t o = ((size_t)b * Q_ + q) * G_ + g;
        out_cost[o] = cost;
        out_iou[o]  = iou;
        ctile[qls][g] = cost;

        if (iou > t4) {
            if (iou > t0)      { t4 = t3; t3 = t2; t2 = t1; t1 = t0; t0 = iou; }
            else if (iou > t1) { t4 = t3; t3 = t2; t2 = t1; t1 = iou; }
            else if (iou > t2) { t4 = t3; t3 = t2; t2 = iou; }
            else if (iou > t3) { t4 = t3; t3 = iou; }
            else               { t4 = iou; }
        }
        const u64 kk = packkey(cost, q);
        if (kk < k4) {
            if (kk < k0)      { k4 = k3; k3 = k2; k2 = k1; k1 = k0; k0 = kk; }
            else if (kk < k1) { k4 = k3; k3 = k2; k2 = k1; k1 = kk; }
            else if (kk < k2) { k4 = k3; k3 = k2; k2 = kk; }
            else if (kk < k3) { k4 = k3; k3 = kk; }
            else              { k4 = kk; }
        }
    }
    __syncthreads();   // ctile complete; lbuf reads done (khalf may overlay)

    // ---- in-kernel row argmin (first-index tie-break), 16 lanes per q ----
    {
        const int qls  = tid >> 4;      // 0..15
        const int part = tid & 15;
        float v = 1e38f; int mg = 0x7fffffff;
        #pragma unroll
        for (int j = 0; j < 8; ++j) {
            const int gg = part + 16 * j;
            const float c = ctile[qls][gg];
            if (c < v || (c == v && gg < mg)) { v = c; mg = gg; }
        }
        #pragma unroll
        for (int off = 1; off < 16; off <<= 1) {
            const float ov = __shfl_xor(v, off);
            const int   og = __shfl_xor(mg, off);
            if (ov < v || (ov == v && og < mg)) { v = ov; mg = og; }
        }
        if (part == 0) ramin[b * Q_ + q0 + qls] = mg;
    }

    // ---- merge q-halves of both partial lists, write per (b, chunk, g) ----
    if (qh == 1) {
        phalf[g][0] = t0; phalf[g][1] = t1; phalf[g][2] = t2;
        phalf[g][3] = t3; phalf[g][4] = t4;
        khalf[g][0] = k0; khalf[g][1] = k1; khalf[g][2] = k2;
        khalf[g][3] = k3; khalf[g][4] = k4;
    }
    __syncthreads();
    if (qh == 0) {
        merge5_desc(t0, t1, t2, t3, t4,
                    phalf[g][0], phalf[g][1], phalf[g][2], phalf[g][3], phalf[g][4]);
        merge5_asc(k0, k1, k2, k3, k4,
                   khalf[g][0], khalf[g][1], khalf[g][2], khalf[g][3], khalf[g][4]);
        // coalesced layout: [B][NCH][G][5]
        const size_t pbase = (((size_t)b * NCH + ci) * G_ + g) * 5;
        piou[pbase + 0] = t0; piou[pbase + 1] = t1; piou[pbase + 2] = t2;
        piou[pbase + 3] = t3; piou[pbase + 4] = t4;
        pcost[pbase + 0] = k0; pcost[pbase + 1] = k1; pcost[pbase + 2] = k2;
        pcost[pbase + 3] = k3; pcost[pbase + 4] = k4;
    }
}

// ---------------------------------------------------------------------------
// Kernel B: per-column (block=256 = one thread per chunk-list): merge 256
// sorted 5-lists (cost keys asc, iou desc) -> cand, dyn_k, scatter.
// ---------------------------------------------------------------------------
__global__ __launch_bounds__(256) void dynk_scatter_kernel(
    const u64*   __restrict__ pcost,
    const float* __restrict__ piou,
    u64* __restrict__ cand,
    int* __restrict__ cnt,
    int* __restrict__ gsel)
{
    const int col = blockIdx.x;          // b*G + g
    const int b = col >> 7, g = col & 127;
    const int tid = threadIdx.x;         // = chunk index ci
    const int wv = tid >> 6, ln = tid & 63;

    __shared__ u64   wl[4][5];
    __shared__ float il[4][5];

    // layout [B][NCH][G][5]
    const size_t base = (((size_t)b * NCH + tid) * G_ + g) * 5;

    u64 k0 = pcost[base + 0], k1 = pcost[base + 1], k2 = pcost[base + 2],
        k3 = pcost[base + 3], k4 = pcost[base + 4];
    float t0 = piou[base + 0], t1 = piou[base + 1], t2 = piou[base + 2],
          t3 = piou[base + 3], t4 = piou[base + 4];

    #pragma unroll
    for (int off = 1; off < 64; off <<= 1) {
        merge5_asc(k0, k1, k2, k3, k4,
                   __shfl_xor(k0, off), __shfl_xor(k1, off), __shfl_xor(k2, off),
                   __shfl_xor(k3, off), __shfl_xor(k4, off));
        merge5_desc(t0, t1, t2, t3, t4,
                    __shfl_xor(t0, off), __shfl_xor(t1, off), __shfl_xor(t2, off),
                    __shfl_xor(t3, off), __shfl_xor(t4, off));
    }
    if (ln == 0) {
        wl[wv][0] = k0; wl[wv][1] = k1; wl[wv][2] = k2; wl[wv][3] = k3; wl[wv][4] = k4;
        il[wv][0] = t0; il[wv][1] = t1; il[wv][2] = t2; il[wv][3] = t3; il[wv][4] = t4;
    }
    __syncthreads();

    if (tid == 0) {
        u64 f0 = wl[0][0], f1 = wl[0][1], f2 = wl[0][2], f3 = wl[0][3], f4 = wl[0][4];
        merge5_asc(f0, f1, f2, f3, f4, wl[1][0], wl[1][1], wl[1][2], wl[1][3], wl[1][4]);
        merge5_asc(f0, f1, f2, f3, f4, wl[2][0], wl[2][1], wl[2][2], wl[2][3], wl[2][4]);
        merge5_asc(f0, f1, f2, f3, f4, wl[3][0], wl[3][1], wl[3][2], wl[3][3], wl[3][4]);
        float s0 = il[0][0], s1 = il[0][1], s2 = il[0][2], s3 = il[0][3], s4 = il[0][4];
        merge5_desc(s0, s1, s2, s3, s4, il[1][0], il[1][1], il[1][2], il[1][3], il[1][4]);
        merge5_desc(s0, s1, s2, s3, s4, il[2][0], il[2][1], il[2][2], il[2][3], il[2][4]);
        merge5_desc(s0, s1, s2, s3, s4, il[3][0], il[3][1], il[3][2], il[3][3], il[3][4]);

        cand[(size_t)col * 5 + 0] = f0;
        cand[(size_t)col * 5 + 1] = f1;
        cand[(size_t)col * 5 + 2] = f2;
        cand[(size_t)col * 5 + 3] = f3;
        cand[(size_t)col * 5 + 4] = f4;

        const float s = s0 + s1 + s2 + s3 + s4;
        int dynk = (int)s;
        if (dynk < 1) dynk = 1;
        if (dynk > 5) dynk = 5;
        const u64 ks[5] = {f0, f1, f2, f3, f4};
        #pragma unroll
        for (int i = 0; i < 5; ++i) {
            if (i < dynk) {
                const int q = (int)(ks[i] & 0xffffffffu);
                atomicAdd(&cnt[b * Q_ + q], 1);
                gsel[b * Q_ + q] = g;   // only read when cnt==1
            }
        }
    }
}

// ---------------------------------------------------------------------------
// Kernel C: per-batch event-driven refinement loop (1024 threads).
// Hits only land on unmatched rows; rows never re-assign; columns never
// unmatch.  Wave-parallel fallback (rare) scans the row-major cost plane
// (strided; L3-resident) and refills the column's candidate list with the
// bottom-5 currently-unmatched rows (prefix-validity argument).
// ---------------------------------------------------------------------------
__global__ __launch_bounds__(1024) void loop_kernel(
    const float* __restrict__ cost,
    const int* __restrict__ cnt,
    const int* __restrict__ gsel,
    const int* __restrict__ ramin,
    const u64* __restrict__ cand,
    int* __restrict__ rmatch_final)
{
    const int b = blockIdx.x, tid = threadIdx.x;
    const int wv = tid >> 6, ln = tid & 63;

    __shared__ short rmatch[Q_];            // 8 KB
    __shared__ unsigned char s_ra[Q_];      // 4 KB
    __shared__ int newh[Q_];                // 16 KB
    __shared__ unsigned char newg[Q_];      // 4 KB
    __shared__ u64 scand[G_][5];            // 5 KB
    __shared__ int ptrs[G_], col_cnt[G_], unm_list[G_], prop[G_], fb_slot[G_], touched[G_];
    __shared__ int n_unm, n_fb, n_touch;

    for (int q = tid; q < Q_; q += 1024) {
        const int c  = cnt[b * Q_ + q];
        const int ra = ramin[b * Q_ + q];
        s_ra[q] = (unsigned char)ra;
        newh[q] = 0;
        rmatch[q] = (c == 0) ? (short)-1
                             : (c == 1 ? (short)gsel[b * Q_ + q] : (short)ra);
    }
    if (tid < G_) { col_cnt[tid] = 0; ptrs[tid] = 0; }
    if (tid < G_ * 5)
        scand[tid / 5][tid % 5] = cand[(size_t)b * G_ * 5 + tid];
    __syncthreads();
    for (int q = tid; q < Q_; q += 1024)
        if (rmatch[q] >= 0) atomicAdd(&col_cnt[rmatch[q]], 1);
    __syncthreads();

    const float* costb = cost + (size_t)b * Q_ * G_;

    for (int it = 0; it < G_; ++it) {
        if (tid == 0) { n_unm = 0; n_fb = 0; n_touch = 0; }
        __syncthreads();
        if (tid < G_ && col_cnt[tid] == 0)
            unm_list[atomicAdd(&n_unm, 1)] = tid;
        __syncthreads();
        const int nu = n_unm;
        if (nu == 0) break;

        // propose: first unmatched candidate, else mark for fallback scan
        if (tid < nu) {
            const int g = unm_list[tid];
            int p = ptrs[g];
            int q = -1;
            while (p < 5) {
                const int cq = (int)(scand[g][p] & 0xffffffffu);
                if (rmatch[cq] < 0) { q = cq; break; }
                ++p;
            }
            ptrs[g] = p;
            prop[tid] = q;
            if (q < 0) fb_slot[atomicAdd(&n_fb, 1)] = tid;
        }
        __syncthreads();

        // wave-parallel fallback (16 waves): bottom-5 unmatched + refill.
        // Strided column read of the row-major cost plane (L3-resident).
        const int nf = n_fb;
        for (int i = wv; i < nf; i += 16) {
            const int slot = fb_slot[i];
            const int g = unm_list[slot];
            const float* colp = costb + g;
            u64 k0 = U64MAX, k1 = U64MAX, k2 = U64MAX, k3 = U64MAX, k4 = U64MAX;
            for (int q = ln; q < Q_; q += 64) {
                if (rmatch[q] < 0) {
                    const float v = colp[(size_t)q * G_];
                    const u64 kk = packkey(v, q);
                    if (kk < k4) {
                        if (kk < k0)      { k4 = k3; k3 = k2; k2 = k1; k1 = k0; k0 = kk; }
                        else if (kk < k1) { k4 = k3; k3 = k2; k2 = k1; k1 = kk; }
                        else if (kk < k2) { k4 = k3; k3 = k2; k2 = kk; }
                        else if (kk < k3) { k4 = k3; k3 = kk; }
                        else              { k4 = kk; }
                    }
                }
            }
            #pragma unroll
            for (int off = 1; off < 64; off <<= 1) {
                merge5_asc(k0, k1, k2, k3, k4,
                           __shfl_xor(k0, off), __shfl_xor(k1, off), __shfl_xor(k2, off),
                           __shfl_xor(k3, off), __shfl_xor(k4, off));
            }
            if (ln == 0) {
                scand[g][0] = k0; scand[g][1] = k1; scand[g][2] = k2;
                scand[g][3] = k3; scand[g][4] = k4;
                ptrs[g] = 0;
                prop[slot] = (int)(k0 & 0xffffffffu);
            }
        }
        __syncthreads();

        // hits
        if (tid < nu) {
            const int q = prop[tid];
            newg[q] = (unsigned char)unm_list[tid];  // consumed only when nh==1
            if (atomicAdd(&newh[q], 1) == 0)
                touched[atomicAdd(&n_touch, 1)] = q;
        }
        __syncthreads();

        // resolve (dedup): hits only land on unmatched rows
        const int nt = n_touch;
        if (tid < nt) {
            const int q = touched[tid];
            const int nh = newh[q];
            const int gg = (nh == 1) ? (int)newg[q] : (int)s_ra[q];
            rmatch[q] = (short)gg;
            atomicAdd(&col_cnt[gg], 1);
            newh[q] = 0;
        }
        __syncthreads();
    }

    for (int q = tid; q < Q_; q += 1024)
        rmatch_final[b * Q_ + q] = rmatch[q];
}

// ---------------------------------------------------------------------------
// Kernel D: expand rmatch -> full match plane (fully parallel float4 writes).
// ---------------------------------------------------------------------------
__global__ __launch_bounds__(256) void expand_kernel(
    const int* __restrict__ rmatch_final, float* __restrict__ out_match)
{
    const int idx = blockIdx.x * 256 + threadIdx.x;  // float4 index
    const int row = idx >> 5;                        // G/4 = 32 float4 per row
    const int gb  = (idx & 31) << 2;
    const int rm  = rmatch_final[row];
    float4 o;
    o.x = (rm == gb)     ? 1.f : 0.f;
    o.y = (rm == gb + 1) ? 1.f : 0.f;
    o.z = (rm == gb + 2) ? 1.f : 0.f;
    o.w = (rm == gb + 3) ? 1.f : 0.f;
    ((float4*)out_match)[idx] = o;
}

extern "C" void kernel_launch(void* const* d_in, const int* in_sizes, int n_in,
                              void* d_out, int out_size, void* d_ws, size_t ws_size,
                              hipStream_t stream) {
    const float* logits  = (const float*)d_in[0];
    const float* pboxes  = (const float*)d_in[1];
    const float* gboxes  = (const float*)d_in[2];
    const int*   glabels = (const int*)d_in[3];

    float* out = (float*)d_out;
    const size_t BQG = (size_t)B_ * Q_ * G_;
    float* out_match = out;
    float* out_cost  = out + BQG;
    float* out_iou   = out + 2 * BQG;

    // workspace layout (~33 MB)
    char* ws = (char*)d_ws;
    size_t off = 0;
    u64*   pcost  = (u64*)  (ws + off); off += (size_t)B_ * NCH * G_ * 5 * 8;
    float* piou   = (float*)(ws + off); off += (size_t)B_ * NCH * G_ * 5 * 4;
    u64*   cand   = (u64*)  (ws + off); off += (size_t)B_ * G_ * 5 * 8;
    int*   ramin  = (int*)  (ws + off); off += (size_t)B_ * Q_ * 4;
    int*   cnt    = (int*)  (ws + off); off += (size_t)B_ * Q_ * 4;
    int*   gsel   = (int*)  (ws + off); off += (size_t)B_ * Q_ * 4;
    int*   rmf    = (int*)  (ws + off); off += (size_t)B_ * Q_ * 4;

    fused_cost_kernel<<<dim3(NCH, B_), 256, 0, stream>>>(
        logits, pboxes, gboxes, glabels, out_cost, out_iou, piou, pcost, ramin, cnt);
    dynk_scatter_kernel<<<B_ * G_, 256, 0, stream>>>(pcost, piou, cand, cnt, gsel);
    loop_kernel<<<B_, 1024, 0, stream>>>(out_cost, cnt, gsel, ramin, cand, rmf);
    expand_kernel<<<(int)(BQG / 4 / 256), 256, 0, stream>>>(rmf, out_match);
}